// Round 1
// baseline (253.255 us; speedup 1.0000x reference)
//
#include <hip/hip_runtime.h>
#include <math.h>

#define N_NODES 20000
#define N_EDGES 160000

// ---- workspace layout (float offsets) ----
#define WS_We0 0            // [8][16]
#define WS_b0m 128          // [16]
#define WS_W0  256          // [80][128]
#define WS_b0  10496        // [128]
#define WS_We1 10624        // [8][128]
#define WS_b1m 11648       // [128]
#define WS_W1  11776        // [640][128]
#define WS_b1  93696        // [128]
#define WS_t0  93824        // [20000][16]
#define WS_u0  413824       // [20000][16]
#define WS_A0  733824       // [20000][80]  (x | mean | max | min | std)
#define WS_h0  2333824      // [20000][128]
#define WS_t1  4893824      // [20000][128]
#define WS_u1  7453824      // [20000][128]
#define WS_h1  10013824     // [20000][128]
// total 12,573,824 floats = 50.3 MB

// ---------------- kernel 1: weight folds + t0/u0 tables ----------------
__global__ __launch_bounds__(256) void k_prep(
    const float* __restrict__ x,
    const float* __restrict__ ew0, const float* __restrict__ eb0,
    const float* __restrict__ pw0, const float* __restrict__ pb0,
    const float* __restrict__ qw0, const float* __restrict__ qb0,
    const float* __restrict__ lw0, const float* __restrict__ lb0,
    const float* __restrict__ ew1, const float* __restrict__ eb1,
    const float* __restrict__ pw1, const float* __restrict__ pb1,
    const float* __restrict__ qw1, const float* __restrict__ qb1,
    const float* __restrict__ lw1, const float* __restrict__ lb1,
    float* __restrict__ ws)
{
    int tid = blockIdx.x * 256 + threadIdx.x;
    if (tid < 81920) {                       // W1 = Q1eff @ lw1   [640][128]
        int r = tid >> 7, o = tid & 127;
        float acc = 0.f;
        for (int h = 0; h < 128; ++h) {
            float qr;
            if (r < 128) qr = qw1[r*128 + h];
            else {
                int s = r - 128;
                qr = qw1[(128+s)*128+h] + qw1[(640+s)*128+h] + qw1[(1152+s)*128+h];
            }
            acc += qr * lw1[h*128 + o];
        }
        ws[WS_W1 + tid] = acc;
    } else if (tid < 82048) {                // b1 = qb1@lw1 + lb1
        int o = tid - 81920;
        float acc = lb1[o];
        for (int h = 0; h < 128; ++h) acc += qb1[h] * lw1[h*128 + o];
        ws[WS_b1 + o] = acc;
    } else if (tid < 92288) {                // W0 = Q0eff @ lw0   [80][128]
        int idx = tid - 82048; int r = idx >> 7, o = idx & 127;
        float acc = 0.f;
        for (int h = 0; h < 128; ++h) {
            float qr;
            if (r < 16) qr = qw0[r*128 + h];
            else {
                int s = r - 16;
                qr = qw0[(16+s)*128+h] + qw0[(80+s)*128+h] + qw0[(144+s)*128+h];
            }
            acc += qr * lw0[h*128 + o];
        }
        ws[WS_W0 + idx] = acc;
    } else if (tid < 92416) {                // b0 = qb0@lw0 + lb0
        int o = tid - 92288;
        float acc = lb0[o];
        for (int h = 0; h < 128; ++h) acc += qb0[h] * lw0[h*128 + o];
        ws[WS_b0 + o] = acc;
    } else if (tid < 93440) {                // We1 = ew1 @ pw1_c  [8][128]
        int idx = tid - 92416; int c = idx >> 7, f = idx & 127;
        float acc = 0.f;
        for (int k = 0; k < 128; ++k) acc += ew1[c*128 + k] * pw1[(256+k)*128 + f];
        ws[WS_We1 + idx] = acc;
    } else if (tid < 93568) {                // b1m = eb1@pw1_c + pb1
        int f = tid - 93440;
        float acc = pb1[f];
        for (int k = 0; k < 128; ++k) acc += eb1[k] * pw1[(256+k)*128 + f];
        ws[WS_b1m + f] = acc;
    } else if (tid < 93696) {                // We0 = ew0 @ pw0_c  [8][16]
        int idx = tid - 93568; int c = idx >> 4, f = idx & 15;
        float acc = 0.f;
        for (int k = 0; k < 16; ++k) acc += ew0[c*16 + k] * pw0[(32+k)*16 + f];
        ws[WS_We0 + idx] = acc;
    } else if (tid < 93712) {                // b0m = eb0@pw0_c + pb0
        int f = tid - 93696;
        float acc = pb0[f];
        for (int k = 0; k < 16; ++k) acc += eb0[k] * pw0[(32+k)*16 + f];
        ws[WS_b0m + f] = acc;
    } else if (tid < 413712) {               // t0 = x @ pw0_a  [20000][16]
        int idx = tid - 93712; int i = idx >> 4, f = idx & 15;
        float acc = 0.f;
        for (int k = 0; k < 16; ++k) acc += x[i*16 + k] * pw0[k*16 + f];
        ws[WS_t0 + idx] = acc;
    } else if (tid < 733712) {               // u0 = x @ pw0_b  [20000][16]
        int idx = tid - 413712; int i = idx >> 4, f = idx & 15;
        float acc = 0.f;
        for (int k = 0; k < 16; ++k) acc += x[i*16 + k] * pw0[(16+k)*16 + f];
        ws[WS_u0 + idx] = acc;
    }
}

// ---------------- kernel 2: layer-0 gather + aggregate -> A0 ----------------
__global__ __launch_bounds__(256) void k_agg0(
    const float* __restrict__ x, const float* __restrict__ ea,
    const int* __restrict__ src, float* __restrict__ ws)
{
    __shared__ float ea_s[16*8*8];   // [n][k][c]
    __shared__ int   src_s[16*8];
    __shared__ float We0_s[128];
    __shared__ float b0m_s[16];
    const int t = threadIdx.x;
    const int i0 = blockIdx.x * 16;

    for (int idx = t; idx < 1024; idx += 256) {
        int k = idx >> 7; int rem = idx & 127; int n = rem >> 3, c = rem & 7;
        ea_s[(n*8 + k)*8 + c] = ea[(i0 + n + k*N_NODES)*8 + c];
    }
    if (t < 128) {
        int k = t >> 4, n = t & 15;
        src_s[n*8 + k] = src[i0 + n + k*N_NODES];
        We0_s[t] = ws[WS_We0 + t];
    }
    if (t < 16) b0m_s[t] = ws[WS_b0m + t];
    __syncthreads();

    const int n = t >> 4, f = t & 15;
    const int i = i0 + n;
    float base = ws[WS_t0 + i*16 + f] + b0m_s[f];
    float s = 0.f, q = 0.f, mx = -1e30f, mn = 1e30f;
    for (int k = 0; k < 8; ++k) {
        int sj = src_s[n*8 + k];
        float m = base + ws[WS_u0 + sj*16 + f];
        #pragma unroll
        for (int c = 0; c < 8; ++c) m += ea_s[(n*8+k)*8 + c] * We0_s[c*16 + f];
        s += m; q += m*m; mx = fmaxf(mx, m); mn = fminf(mn, m);
    }
    float mean = s * 0.125f, mean2 = q * 0.125f;
    float sd = sqrtf(fmaxf(mean2 - mean*mean, 0.f) + 1e-5f);
    float* A0 = ws + WS_A0 + (size_t)i * 80;
    A0[f]      = x[i*16 + f];
    A0[16 + f] = mean;
    A0[32 + f] = mx;
    A0[48 + f] = mn;
    A0[64 + f] = sd;
}

// ---------------- kernel 3: h0 = relu(LN(A0 @ W0 + b0)) ----------------
__global__ __launch_bounds__(256) void k_gemm0(
    const float* __restrict__ g0, const float* __restrict__ bln0,
    float* __restrict__ ws)
{
    __shared__ float As[32][81];
    const int t = threadIdx.x;
    const int r0 = blockIdx.x * 32;
    const float* A = ws + WS_A0 + (size_t)r0 * 80;
    for (int idx = t; idx < 32*80; idx += 256) {
        int r = idx / 80, k = idx - r*80;
        As[r][k] = A[idx];
    }
    __syncthreads();
    const int tc = t & 31, tr = t >> 5;
    const int c0 = tc * 4;
    float acc[4][4] = {};
    const float* W = ws + WS_W0;
    #pragma unroll 4
    for (int k = 0; k < 80; ++k) {
        float4 b = *(const float4*)(W + k*128 + c0);
        #pragma unroll
        for (int rr = 0; rr < 4; ++rr) {
            float a = As[tr*4 + rr][k];
            acc[rr][0] += a*b.x; acc[rr][1] += a*b.y;
            acc[rr][2] += a*b.z; acc[rr][3] += a*b.w;
        }
    }
    float4 bias = *(const float4*)(ws + WS_b0 + c0);
    float4 g  = *(const float4*)(g0 + c0);
    float4 bb = *(const float4*)(bln0 + c0);
    #pragma unroll
    for (int rr = 0; rr < 4; ++rr) {
        float v0 = acc[rr][0] + bias.x, v1 = acc[rr][1] + bias.y;
        float v2 = acc[rr][2] + bias.z, v3 = acc[rr][3] + bias.w;
        float sum = v0+v1+v2+v3;
        float sq  = v0*v0+v1*v1+v2*v2+v3*v3;
        #pragma unroll
        for (int off = 1; off < 32; off <<= 1) {
            sum += __shfl_xor(sum, off, 64);
            sq  += __shfl_xor(sq,  off, 64);
        }
        float mean = sum * (1.f/128.f);
        float var  = sq  * (1.f/128.f) - mean*mean;
        float rstd = rsqrtf(var + 1e-5f);
        float4 o;
        o.x = fmaxf((v0-mean)*rstd*g.x + bb.x, 0.f);
        o.y = fmaxf((v1-mean)*rstd*g.y + bb.y, 0.f);
        o.z = fmaxf((v2-mean)*rstd*g.z + bb.z, 0.f);
        o.w = fmaxf((v3-mean)*rstd*g.w + bb.w, 0.f);
        *(float4*)(ws + WS_h0 + (size_t)(r0 + tr*4 + rr)*128 + c0) = o;
    }
}

// ---------------- kernel 4: t1 = h0 @ pw1[0:128], u1 = h0 @ pw1[128:256] ----------------
__global__ __launch_bounds__(256) void k_tu1(
    const float* __restrict__ pw1, float* __restrict__ ws)
{
    __shared__ float As[32][133];
    const int t = threadIdx.x;
    const int r0 = blockIdx.x * 32;
    const float* A = ws + WS_h0 + (size_t)r0 * 128;
    for (int idx = t; idx < 32*128; idx += 256) {
        int r = idx >> 7, k = idx & 127;
        As[r][k] = A[idx];
    }
    __syncthreads();
    const int tc = t & 31, tr = t >> 5;
    const int c0 = tc * 4;
    float acct[4][4] = {}, accu[4][4] = {};
    #pragma unroll 4
    for (int k = 0; k < 128; ++k) {
        float4 bt = *(const float4*)(pw1 + k*128 + c0);
        float4 bu = *(const float4*)(pw1 + (128+k)*128 + c0);
        #pragma unroll
        for (int rr = 0; rr < 4; ++rr) {
            float a = As[tr*4 + rr][k];
            acct[rr][0] += a*bt.x; acct[rr][1] += a*bt.y;
            acct[rr][2] += a*bt.z; acct[rr][3] += a*bt.w;
            accu[rr][0] += a*bu.x; accu[rr][1] += a*bu.y;
            accu[rr][2] += a*bu.z; accu[rr][3] += a*bu.w;
        }
    }
    #pragma unroll
    for (int rr = 0; rr < 4; ++rr) {
        size_t row = (size_t)(r0 + tr*4 + rr) * 128 + c0;
        float4 ot = {acct[rr][0], acct[rr][1], acct[rr][2], acct[rr][3]};
        float4 ou = {accu[rr][0], accu[rr][1], accu[rr][2], accu[rr][3]};
        *(float4*)(ws + WS_t1 + row) = ot;
        *(float4*)(ws + WS_u1 + row) = ou;
    }
}

// ---------------- kernel 5: fused layer-1 aggregate + GEMM(K=640) + LN + relu ----------------
__global__ __launch_bounds__(256) void k_gemm1(
    const float* __restrict__ ea, const int* __restrict__ src,
    const float* __restrict__ g1, const float* __restrict__ bln1,
    float* __restrict__ ws)
{
    __shared__ float h0s[16][132];
    __shared__ float aggs[16][516];
    __shared__ float ea_s[16*8*8];
    __shared__ int   src_s[16*8];
    __shared__ float We1_s[8*128];
    __shared__ float b1m_s[128];
    const int t = threadIdx.x;
    const int i0 = blockIdx.x * 16;

    for (int idx = t; idx < 1024; idx += 256) {
        int k = idx >> 7; int rem = idx & 127; int n = rem >> 3, c = rem & 7;
        ea_s[(n*8 + k)*8 + c] = ea[(i0 + n + k*N_NODES)*8 + c];
    }
    if (t < 128) {
        int k = t >> 4, n = t & 15;
        src_s[n*8 + k] = src[i0 + n + k*N_NODES];
    }
    for (int idx = t; idx < 1024; idx += 256) We1_s[idx] = ws[WS_We1 + idx];
    if (t < 128) b1m_s[t] = ws[WS_b1m + t];
    for (int idx = t; idx < 2048; idx += 256) {
        int n = idx >> 7, k = idx & 127;
        h0s[n][k] = ws[WS_h0 + (size_t)(i0 + n)*128 + k];
    }
    __syncthreads();

    { // phase A: per-node aggregation (16 threads/node, 8 features each)
        const int n = t >> 4, sub = t & 15;
        const int i = i0 + n;
        const int f0 = sub * 8;
        float base[8], sm[8], sq[8], mx[8], mn[8];
        #pragma unroll
        for (int e = 0; e < 8; ++e) {
            base[e] = ws[WS_t1 + (size_t)i*128 + f0 + e] + b1m_s[f0 + e];
            sm[e] = 0.f; sq[e] = 0.f; mx[e] = -1e30f; mn[e] = 1e30f;
        }
        for (int k = 0; k < 8; ++k) {
            int sj = src_s[n*8 + k];
            const float* urow = ws + WS_u1 + (size_t)sj*128 + f0;
            float m[8];
            #pragma unroll
            for (int e = 0; e < 8; ++e) m[e] = base[e] + urow[e];
            #pragma unroll
            for (int c = 0; c < 8; ++c) {
                float a = ea_s[(n*8 + k)*8 + c];
                #pragma unroll
                for (int e = 0; e < 8; ++e) m[e] += a * We1_s[c*128 + f0 + e];
            }
            #pragma unroll
            for (int e = 0; e < 8; ++e) {
                sm[e] += m[e]; sq[e] += m[e]*m[e];
                mx[e] = fmaxf(mx[e], m[e]); mn[e] = fminf(mn[e], m[e]);
            }
        }
        #pragma unroll
        for (int e = 0; e < 8; ++e) {
            float mean = sm[e]*0.125f, m2 = sq[e]*0.125f;
            float sd = sqrtf(fmaxf(m2 - mean*mean, 0.f) + 1e-5f);
            aggs[n][f0 + e]        = mean;
            aggs[n][128 + f0 + e]  = mx[e];
            aggs[n][256 + f0 + e]  = mn[e];
            aggs[n][384 + f0 + e]  = sd;
        }
    }
    __syncthreads();

    // phase B: [16 x 640] @ W1[640 x 128]
    const int tc = t & 31, tr = t >> 5;
    const int c0 = tc * 4;
    const int ra = tr*2, rb = tr*2 + 1;
    float acc[2][4] = {};
    const float* W = ws + WS_W1;
    #pragma unroll 4
    for (int k = 0; k < 128; ++k) {
        float4 b = *(const float4*)(W + (size_t)k*128 + c0);
        float a0 = h0s[ra][k], a1 = h0s[rb][k];
        acc[0][0]+=a0*b.x; acc[0][1]+=a0*b.y; acc[0][2]+=a0*b.z; acc[0][3]+=a0*b.w;
        acc[1][0]+=a1*b.x; acc[1][1]+=a1*b.y; acc[1][2]+=a1*b.z; acc[1][3]+=a1*b.w;
    }
    #pragma unroll 4
    for (int k = 0; k < 512; ++k) {
        float4 b = *(const float4*)(W + (size_t)(128+k)*128 + c0);
        float a0 = aggs[ra][k], a1 = aggs[rb][k];
        acc[0][0]+=a0*b.x; acc[0][1]+=a0*b.y; acc[0][2]+=a0*b.z; acc[0][3]+=a0*b.w;
        acc[1][0]+=a1*b.x; acc[1][1]+=a1*b.y; acc[1][2]+=a1*b.z; acc[1][3]+=a1*b.w;
    }
    float4 bias = *(const float4*)(ws + WS_b1 + c0);
    float4 g  = *(const float4*)(g1 + c0);
    float4 bb = *(const float4*)(bln1 + c0);
    #pragma unroll
    for (int rr = 0; rr < 2; ++rr) {
        float v0 = acc[rr][0] + bias.x, v1 = acc[rr][1] + bias.y;
        float v2 = acc[rr][2] + bias.z, v3 = acc[rr][3] + bias.w;
        float sum = v0+v1+v2+v3;
        float sq  = v0*v0+v1*v1+v2*v2+v3*v3;
        #pragma unroll
        for (int off = 1; off < 32; off <<= 1) {
            sum += __shfl_xor(sum, off, 64);
            sq  += __shfl_xor(sq,  off, 64);
        }
        float mean = sum * (1.f/128.f);
        float var  = sq  * (1.f/128.f) - mean*mean;
        float rstd = rsqrtf(var + 1e-5f);
        float4 o;
        o.x = fmaxf((v0-mean)*rstd*g.x + bb.x, 0.f);
        o.y = fmaxf((v1-mean)*rstd*g.y + bb.y, 0.f);
        o.z = fmaxf((v2-mean)*rstd*g.z + bb.z, 0.f);
        o.w = fmaxf((v3-mean)*rstd*g.w + bb.w, 0.f);
        *(float4*)(ws + WS_h1 + (size_t)(i0 + tr*2 + rr)*128 + c0) = o;
    }
}

// ---------------- kernel 6: out = h1 @ hw + hb ----------------
__global__ __launch_bounds__(256) void k_head(
    const float* __restrict__ hw, const float* __restrict__ hb,
    const float* __restrict__ ws, float* __restrict__ out)
{
    int tid = blockIdx.x * 256 + threadIdx.x;
    if (tid >= N_NODES * 4) return;
    int r = tid >> 2, o = tid & 3;
    const float* h = ws + WS_h1 + (size_t)r * 128;
    float acc = hb[o];
    #pragma unroll 8
    for (int f = 0; f < 128; ++f) acc += h[f] * hw[f*4 + o];
    out[tid] = acc;
}

extern "C" void kernel_launch(void* const* d_in, const int* in_sizes, int n_in,
                              void* d_out, int out_size, void* d_ws, size_t ws_size,
                              hipStream_t stream)
{
    const float* x    = (const float*)d_in[0];
    const float* ea   = (const float*)d_in[1];
    const int*   eidx = (const int*)d_in[2];
    const float* ew0  = (const float*)d_in[3];
    const float* eb0  = (const float*)d_in[4];
    const float* pw0  = (const float*)d_in[5];
    const float* pb0  = (const float*)d_in[6];
    const float* qw0  = (const float*)d_in[7];
    const float* qb0  = (const float*)d_in[8];
    const float* lw0  = (const float*)d_in[9];
    const float* lb0  = (const float*)d_in[10];
    const float* g0   = (const float*)d_in[11];
    const float* bl0  = (const float*)d_in[12];
    const float* ew1  = (const float*)d_in[13];
    const float* eb1  = (const float*)d_in[14];
    const float* pw1  = (const float*)d_in[15];
    const float* pb1  = (const float*)d_in[16];
    const float* qw1  = (const float*)d_in[17];
    const float* qb1  = (const float*)d_in[18];
    const float* lw1  = (const float*)d_in[19];
    const float* lb1  = (const float*)d_in[20];
    const float* g1   = (const float*)d_in[21];
    const float* bl1  = (const float*)d_in[22];
    const float* hw   = (const float*)d_in[23];
    const float* hb   = (const float*)d_in[24];
    const int* src = eidx;              // edge_index[0] = first E entries
    float* ws = (float*)d_ws;
    float* out = (float*)d_out;

    k_prep<<<2867, 256, 0, stream>>>(x, ew0, eb0, pw0, pb0, qw0, qb0, lw0, lb0,
                                     ew1, eb1, pw1, pb1, qw1, qb1, lw1, lb1, ws);
    k_agg0<<<1250, 256, 0, stream>>>(x, ea, src, ws);
    k_gemm0<<<625, 256, 0, stream>>>(g0, bl0, ws);
    k_tu1<<<625, 256, 0, stream>>>(pw1, ws);
    k_gemm1<<<1250, 256, 0, stream>>>(ea, src, g1, bl1, ws);
    k_head<<<313, 256, 0, stream>>>(hw, hb, ws, out);
}

// Round 2
// 108.575 us; speedup vs baseline: 2.3325x; 2.3325x over previous
//
#include <hip/hip_runtime.h>
#include <math.h>

#define N_NODES 20000
#define N_EDGES 160000

typedef unsigned short ushort_t;
typedef __attribute__((ext_vector_type(8))) short short8v;   // 8 bf16 = 4 VGPR
typedef __attribute__((ext_vector_type(4))) float f32x4;

// ---- workspace layout (float offsets) ----
#define WS_We0  0         // [8][16]
#define WS_b0m  128       // [16]
#define WS_W0   256       // [80][128]
#define WS_b0   10496     // [128]
#define WS_We1  10624     // [8][128]
#define WS_b1m  11648     // [128]
#define WS_W1   11776     // [640][128] f32 (folded)
#define WS_b1   93696     // [128]
#define WS_WP1  93824     // Wpack1: 81920 bf16 = 40960 f  (B frags for gemm1)
#define WS_WPTU 134784    // Wpacktu: 32768 bf16 = 16384 f (B frags for tu1)
#define WS_t0   151168    // f32 [20000][16]
#define WS_u0   471168    // f32 [20000][16]
#define WS_A0   791168    // f32 [20000][80]
#define WS_A1   151168    // bf16 [20000][512] OVERLAYS t0/u0/A0 (dead by then); ends 5271168
#define WS_h0b  5271296   // bf16 [20000][128] = 1280000 f
#define WS_t1   6551296   // f32 [20000][128]
#define WS_u1   9111296   // f32 [20000][128]
// total 11,671,296 floats = 46.7 MB (< previously-accepted 50.3 MB)

__device__ inline ushort_t f2bf(float f) {   // round-to-nearest-even f32->bf16
    union { float f; unsigned u; } v; v.f = f;
    unsigned r = v.u + 0x7FFFu + ((v.u >> 16) & 1u);
    return (ushort_t)(r >> 16);
}

// ---------------- kernel 1: weight folds + t0/u0 tables (f32) ----------------
__global__ __launch_bounds__(256) void k_prep(
    const float* __restrict__ x,
    const float* __restrict__ ew0, const float* __restrict__ eb0,
    const float* __restrict__ pw0, const float* __restrict__ pb0,
    const float* __restrict__ qw0, const float* __restrict__ qb0,
    const float* __restrict__ lw0, const float* __restrict__ lb0,
    const float* __restrict__ ew1, const float* __restrict__ eb1,
    const float* __restrict__ pw1, const float* __restrict__ pb1,
    const float* __restrict__ qw1, const float* __restrict__ qb1,
    const float* __restrict__ lw1, const float* __restrict__ lb1,
    float* __restrict__ ws)
{
    int tid = blockIdx.x * 256 + threadIdx.x;
    if (tid < 81920) {                       // W1 = Q1eff @ lw1   [640][128]
        int r = tid >> 7, o = tid & 127;
        float acc = 0.f;
        for (int h = 0; h < 128; ++h) {
            float qr;
            if (r < 128) qr = qw1[r*128 + h];
            else {
                int s = r - 128;
                qr = qw1[(128+s)*128+h] + qw1[(640+s)*128+h] + qw1[(1152+s)*128+h];
            }
            acc += qr * lw1[h*128 + o];
        }
        ws[WS_W1 + tid] = acc;
    } else if (tid < 82048) {                // b1 = qb1@lw1 + lb1
        int o = tid - 81920;
        float acc = lb1[o];
        for (int h = 0; h < 128; ++h) acc += qb1[h] * lw1[h*128 + o];
        ws[WS_b1 + o] = acc;
    } else if (tid < 92288) {                // W0 = Q0eff @ lw0   [80][128]
        int idx = tid - 82048; int r = idx >> 7, o = idx & 127;
        float acc = 0.f;
        for (int h = 0; h < 128; ++h) {
            float qr;
            if (r < 16) qr = qw0[r*128 + h];
            else {
                int s = r - 16;
                qr = qw0[(16+s)*128+h] + qw0[(80+s)*128+h] + qw0[(144+s)*128+h];
            }
            acc += qr * lw0[h*128 + o];
        }
        ws[WS_W0 + idx] = acc;
    } else if (tid < 92416) {                // b0 = qb0@lw0 + lb0
        int o = tid - 92288;
        float acc = lb0[o];
        for (int h = 0; h < 128; ++h) acc += qb0[h] * lw0[h*128 + o];
        ws[WS_b0 + o] = acc;
    } else if (tid < 93440) {                // We1 = ew1 @ pw1_c  [8][128]
        int idx = tid - 92416; int c = idx >> 7, f = idx & 127;
        float acc = 0.f;
        for (int k = 0; k < 128; ++k) acc += ew1[c*128 + k] * pw1[(256+k)*128 + f];
        ws[WS_We1 + idx] = acc;
    } else if (tid < 93568) {                // b1m = eb1@pw1_c + pb1
        int f = tid - 93440;
        float acc = pb1[f];
        for (int k = 0; k < 128; ++k) acc += eb1[k] * pw1[(256+k)*128 + f];
        ws[WS_b1m + f] = acc;
    } else if (tid < 93696) {                // We0 = ew0 @ pw0_c  [8][16]
        int idx = tid - 93568; int c = idx >> 4, f = idx & 15;
        float acc = 0.f;
        for (int k = 0; k < 16; ++k) acc += ew0[c*16 + k] * pw0[(32+k)*16 + f];
        ws[WS_We0 + idx] = acc;
    } else if (tid < 93712) {                // b0m = eb0@pw0_c + pb0
        int f = tid - 93696;
        float acc = pb0[f];
        for (int k = 0; k < 16; ++k) acc += eb0[k] * pw0[(32+k)*16 + f];
        ws[WS_b0m + f] = acc;
    } else if (tid < 413712) {               // t0 = x @ pw0_a  [20000][16]
        int idx = tid - 93712; int i = idx >> 4, f = idx & 15;
        float acc = 0.f;
        for (int k = 0; k < 16; ++k) acc += x[i*16 + k] * pw0[k*16 + f];
        ws[WS_t0 + idx] = acc;
    } else if (tid < 733712) {               // u0 = x @ pw0_b  [20000][16]
        int idx = tid - 413712; int i = idx >> 4, f = idx & 15;
        float acc = 0.f;
        for (int k = 0; k < 16; ++k) acc += x[i*16 + k] * pw0[(16+k)*16 + f];
        ws[WS_u0 + idx] = acc;
    }
}

// ---------------- kernel 1b: pack B-operand fragments to bf16 ----------------
// Fragment map (assumed, consistently for A and B so k-permutation cancels):
// lane l holds elems j=0..7 with k = (l>>4)*8 + j; B col = ct*16 + (l&15).
__global__ __launch_bounds__(256) void k_pack(
    const float* __restrict__ pw1, float* __restrict__ ws)
{
    int tid = blockIdx.x * 256 + threadIdx.x;
    if (tid < 10240) {          // Wpack1: [(ct*20+ks)*64 + l][8] from folded W1
        ushort_t* WP1 = (ushort_t*)(ws + WS_WP1);
        const float* W1f = ws + WS_W1;
        int l = tid & 63, ctks = tid >> 6;
        int ct = ctks / 20, ks = ctks % 20;
        int col = ct*16 + (l & 15);
        int k0 = ks*32 + (l >> 4)*8;
        short8v v;
        #pragma unroll
        for (int j = 0; j < 8; ++j) v[j] = (short)f2bf(W1f[(k0+j)*128 + col]);
        *(short8v*)(WP1 + (size_t)tid*8) = v;
    } else if (tid < 14336) {   // Wpacktu: ct<8 -> t (pw1 rows 0..127), ct>=8 -> u (128..255)
        int idx = tid - 10240;
        ushort_t* WPT = (ushort_t*)(ws + WS_WPTU);
        int l = idx & 63, ctks = idx >> 6;
        int ct = ctks >> 2, ks = ctks & 3;
        int base_k = (ct < 8) ? 0 : 128;
        int col = (ct & 7)*16 + (l & 15);
        int k0 = base_k + ks*32 + (l >> 4)*8;
        short8v v;
        #pragma unroll
        for (int j = 0; j < 8; ++j) v[j] = (short)f2bf(pw1[(k0+j)*128 + col]);
        *(short8v*)(WPT + (size_t)idx*8) = v;
    }
}

// ---------------- kernel 2: layer-0 gather + aggregate -> A0 (f32) ----------------
__global__ __launch_bounds__(256) void k_agg0(
    const float* __restrict__ x, const float* __restrict__ ea,
    const int* __restrict__ src, float* __restrict__ ws)
{
    __shared__ float ea_s[16*8*8];   // [n][k][c]
    __shared__ int   src_s[16*8];
    __shared__ float We0_s[128];
    __shared__ float b0m_s[16];
    const int t = threadIdx.x;
    const int i0 = blockIdx.x * 16;

    for (int idx = t; idx < 1024; idx += 256) {
        int k = idx >> 7; int rem = idx & 127; int n = rem >> 3, c = rem & 7;
        ea_s[(n*8 + k)*8 + c] = ea[(i0 + n + k*N_NODES)*8 + c];
    }
    if (t < 128) {
        int k = t >> 4, n = t & 15;
        src_s[n*8 + k] = src[i0 + n + k*N_NODES];
        We0_s[t] = ws[WS_We0 + t];
    }
    if (t < 16) b0m_s[t] = ws[WS_b0m + t];
    __syncthreads();

    const int n = t >> 4, f = t & 15;
    const int i = i0 + n;
    float base = ws[WS_t0 + i*16 + f] + b0m_s[f];
    float s = 0.f, q = 0.f, mx = -1e30f, mn = 1e30f;
    for (int k = 0; k < 8; ++k) {
        int sj = src_s[n*8 + k];
        float m = base + ws[WS_u0 + sj*16 + f];
        #pragma unroll
        for (int c = 0; c < 8; ++c) m += ea_s[(n*8+k)*8 + c] * We0_s[c*16 + f];
        s += m; q += m*m; mx = fmaxf(mx, m); mn = fminf(mn, m);
    }
    float mean = s * 0.125f, mean2 = q * 0.125f;
    float sd = sqrtf(fmaxf(mean2 - mean*mean, 0.f) + 1e-5f);
    float* A0 = ws + WS_A0 + (size_t)i * 80;
    A0[f]      = x[i*16 + f];
    A0[16 + f] = mean;
    A0[32 + f] = mx;
    A0[48 + f] = mn;
    A0[64 + f] = sd;
}

// ---------------- kernel 3: h0b = bf16(relu(LN(A0 @ W0 + b0))) ----------------
__global__ __launch_bounds__(256) void k_gemm0(
    const float* __restrict__ g0, const float* __restrict__ bln0,
    float* __restrict__ ws)
{
    __shared__ float As[32][81];
    const int t = threadIdx.x;
    const int r0 = blockIdx.x * 32;
    const float* A = ws + WS_A0 + (size_t)r0 * 80;
    for (int idx = t; idx < 32*80; idx += 256) {
        int r = idx / 80, k = idx - r*80;
        As[r][k] = A[idx];
    }
    __syncthreads();
    const int tc = t & 31, tr = t >> 5;
    const int c0 = tc * 4;
    float acc[4][4] = {};
    const float* W = ws + WS_W0;
    #pragma unroll 4
    for (int k = 0; k < 80; ++k) {
        float4 b = *(const float4*)(W + k*128 + c0);
        #pragma unroll
        for (int rr = 0; rr < 4; ++rr) {
            float a = As[tr*4 + rr][k];
            acc[rr][0] += a*b.x; acc[rr][1] += a*b.y;
            acc[rr][2] += a*b.z; acc[rr][3] += a*b.w;
        }
    }
    float4 bias = *(const float4*)(ws + WS_b0 + c0);
    float4 g  = *(const float4*)(g0 + c0);
    float4 bb = *(const float4*)(bln0 + c0);
    ushort_t* h0b = (ushort_t*)(ws + WS_h0b);
    #pragma unroll
    for (int rr = 0; rr < 4; ++rr) {
        float v0 = acc[rr][0] + bias.x, v1 = acc[rr][1] + bias.y;
        float v2 = acc[rr][2] + bias.z, v3 = acc[rr][3] + bias.w;
        float sum = v0+v1+v2+v3;
        float sq  = v0*v0+v1*v1+v2*v2+v3*v3;
        #pragma unroll
        for (int off = 1; off < 32; off <<= 1) {
            sum += __shfl_xor(sum, off, 64);
            sq  += __shfl_xor(sq,  off, 64);
        }
        float mean = sum * (1.f/128.f);
        float var  = sq  * (1.f/128.f) - mean*mean;
        float rstd = rsqrtf(var + 1e-5f);
        ushort4 ob;
        ob.x = f2bf(fmaxf((v0-mean)*rstd*g.x + bb.x, 0.f));
        ob.y = f2bf(fmaxf((v1-mean)*rstd*g.y + bb.y, 0.f));
        ob.z = f2bf(fmaxf((v2-mean)*rstd*g.z + bb.z, 0.f));
        ob.w = f2bf(fmaxf((v3-mean)*rstd*g.w + bb.w, 0.f));
        *(ushort4*)(h0b + (size_t)(r0 + tr*4 + rr)*128 + c0) = ob;
    }
}

// ---------------- kernel 4: t1/u1 = h0 @ pw1[a|b]  (bf16 MFMA, f32 out) ----------------
__global__ __launch_bounds__(64) void k_tu1(float* __restrict__ ws)
{
    const int lane = threadIdx.x;
    const int rowbase = blockIdx.x * 16;
    const ushort_t* h0b = (const ushort_t*)(ws + WS_h0b);
    const ushort_t* WP  = (const ushort_t*)(ws + WS_WPTU);
    const int lr = lane & 15, lk = lane >> 4;
    const size_t arow = rowbase + lr;
    f32x4 acc[16];
    #pragma unroll
    for (int c = 0; c < 16; ++c) acc[c] = (f32x4){0.f,0.f,0.f,0.f};

    #pragma unroll
    for (int ks = 0; ks < 4; ++ks) {
        short8v a = *(const short8v*)(h0b + arow*128 + ks*32 + lk*8);
        #pragma unroll
        for (int c = 0; c < 16; ++c) {
            short8v b = *(const short8v*)(WP + ((size_t)(c*4 + ks)*64 + lane)*8);
            acc[c] = __builtin_amdgcn_mfma_f32_16x16x32_bf16(a, b, acc[c], 0, 0, 0);
        }
    }
    float* t1 = ws + WS_t1;
    float* u1 = ws + WS_u1;
    #pragma unroll
    for (int c = 0; c < 16; ++c) {
        float* dst = (c < 8) ? t1 : u1;
        int cb = (c & 7)*16 + lr;
        #pragma unroll
        for (int r = 0; r < 4; ++r) {
            int row = rowbase + lk*4 + r;          // C/D map: col=lane&15, row=(lane>>4)*4+reg
            dst[(size_t)row*128 + cb] = acc[c][r];
        }
    }
}

// ---------------- kernel 5: layer-1 aggregate -> A1 bf16 [20000][512] ----------------
__global__ __launch_bounds__(256) void k_agg1(
    const float* __restrict__ ea, const int* __restrict__ src,
    float* __restrict__ ws)
{
    __shared__ float ea_s[16*8*8];
    __shared__ int   src_s[128];
    __shared__ float We1_s[1024];
    __shared__ float b1m_s[128];
    const int t = threadIdx.x;
    const int i0 = blockIdx.x * 16;

    for (int idx = t; idx < 1024; idx += 256) {
        int k = idx >> 7; int rem = idx & 127; int n = rem >> 3, c = rem & 7;
        ea_s[(n*8 + k)*8 + c] = ea[(i0 + n + k*N_NODES)*8 + c];
    }
    if (t < 128) {
        int k = t >> 4, n = t & 15;
        src_s[n*8 + k] = src[i0 + n + k*N_NODES];
    }
    for (int idx = t; idx < 1024; idx += 256) We1_s[idx] = ws[WS_We1 + idx];
    if (t < 128) b1m_s[t] = ws[WS_b1m + t];
    __syncthreads();

    const int n = t >> 4, f0 = (t & 15) * 8;
    const int i = i0 + n;
    float base[8], sm[8], sq[8], mx[8], mn[8];
    #pragma unroll
    for (int e = 0; e < 8; ++e) {
        base[e] = ws[WS_t1 + (size_t)i*128 + f0 + e] + b1m_s[f0 + e];
        sm[e] = 0.f; sq[e] = 0.f; mx[e] = -1e30f; mn[e] = 1e30f;
    }
    for (int k = 0; k < 8; ++k) {
        int sj = src_s[n*8 + k];
        const float* urow = ws + WS_u1 + (size_t)sj*128 + f0;
        float m[8];
        #pragma unroll
        for (int e = 0; e < 8; ++e) m[e] = base[e] + urow[e];
        #pragma unroll
        for (int c = 0; c < 8; ++c) {
            float a = ea_s[(n*8 + k)*8 + c];
            #pragma unroll
            for (int e = 0; e < 8; ++e) m[e] += a * We1_s[c*128 + f0 + e];
        }
        #pragma unroll
        for (int e = 0; e < 8; ++e) {
            sm[e] += m[e]; sq[e] += m[e]*m[e];
            mx[e] = fmaxf(mx[e], m[e]); mn[e] = fminf(mn[e], m[e]);
        }
    }
    ushort_t* A1 = (ushort_t*)(ws + WS_A1);
    short8v vm, vx, vn, vs;
    #pragma unroll
    for (int e = 0; e < 8; ++e) {
        float mean = sm[e]*0.125f, m2 = sq[e]*0.125f;
        float sd = sqrtf(fmaxf(m2 - mean*mean, 0.f) + 1e-5f);
        vm[e] = (short)f2bf(mean);
        vx[e] = (short)f2bf(mx[e]);
        vn[e] = (short)f2bf(mn[e]);
        vs[e] = (short)f2bf(sd);
    }
    size_t b = (size_t)i*512 + f0;
    *(short8v*)(A1 + b)       = vm;
    *(short8v*)(A1 + b + 128) = vx;
    *(short8v*)(A1 + b + 256) = vn;
    *(short8v*)(A1 + b + 384) = vs;
}

// ------- kernel 6: h1 = relu(LN(cat(h0,agg) @ W1 + b1)); out = h1@hw + hb (fused) -------
__global__ __launch_bounds__(64) void k_gemm1(
    const float* __restrict__ g1, const float* __restrict__ bln1,
    const float* __restrict__ hw, const float* __restrict__ hb,
    float* __restrict__ ws, float* __restrict__ out)
{
    const int lane = threadIdx.x;
    const int rowbase = blockIdx.x * 16;
    const ushort_t* h0b = (const ushort_t*)(ws + WS_h0b);
    const ushort_t* A1  = (const ushort_t*)(ws + WS_A1);
    const ushort_t* WP  = (const ushort_t*)(ws + WS_WP1);
    const int lr = lane & 15, lk = lane >> 4;
    const size_t arow = rowbase + lr;

    f32x4 acc[8];
    #pragma unroll
    for (int c = 0; c < 8; ++c) acc[c] = (f32x4){0.f,0.f,0.f,0.f};

    #pragma unroll
    for (int ks = 0; ks < 4; ++ks) {          // K 0..127 from h0b
        short8v a = *(const short8v*)(h0b + arow*128 + ks*32 + lk*8);
        #pragma unroll
        for (int c = 0; c < 8; ++c) {
            short8v b = *(const short8v*)(WP + ((size_t)(c*20 + ks)*64 + lane)*8);
            acc[c] = __builtin_amdgcn_mfma_f32_16x16x32_bf16(a, b, acc[c], 0, 0, 0);
        }
    }
    #pragma unroll 4
    for (int ks = 0; ks < 16; ++ks) {         // K 128..639 from A1
        short8v a = *(const short8v*)(A1 + arow*512 + ks*32 + lk*8);
        #pragma unroll
        for (int c = 0; c < 8; ++c) {
            short8v b = *(const short8v*)(WP + ((size_t)(c*20 + 4 + ks)*64 + lane)*8);
            acc[c] = __builtin_amdgcn_mfma_f32_16x16x32_bf16(a, b, acc[c], 0, 0, 0);
        }
    }

    // epilogue: +bias, LayerNorm over 128 cols (16-lane butterfly), relu, head GEMV
    float bc[8], gc[8], bbc[8]; f32x4 hwc[8];
    #pragma unroll
    for (int c = 0; c < 8; ++c) {
        int col = c*16 + lr;
        bc[c]  = ws[WS_b1 + col];
        gc[c]  = g1[col];
        bbc[c] = bln1[col];
        hwc[c] = *(const f32x4*)(hw + col*4);
    }
    f32x4 hb4 = *(const f32x4*)hb;
    #pragma unroll
    for (int r = 0; r < 4; ++r) {
        float v[8]; float s = 0.f, q = 0.f;
        #pragma unroll
        for (int c = 0; c < 8; ++c) {
            v[c] = acc[c][r] + bc[c];
            s += v[c]; q += v[c]*v[c];
        }
        #pragma unroll
        for (int off = 1; off < 16; off <<= 1) {
            s += __shfl_xor(s, off, 64);
            q += __shfl_xor(q, off, 64);
        }
        float mean = s * (1.f/128.f);
        float var  = q * (1.f/128.f) - mean*mean;
        float rstd = rsqrtf(var + 1e-5f);
        f32x4 po = (f32x4){0.f,0.f,0.f,0.f};
        #pragma unroll
        for (int c = 0; c < 8; ++c) {
            float o = fmaxf((v[c]-mean)*rstd*gc[c] + bbc[c], 0.f);
            po += o * hwc[c];
        }
        #pragma unroll
        for (int off = 1; off < 16; off <<= 1) {
            po.x += __shfl_xor(po.x, off, 64);
            po.y += __shfl_xor(po.y, off, 64);
            po.z += __shfl_xor(po.z, off, 64);
            po.w += __shfl_xor(po.w, off, 64);
        }
        if (lr == 0) {
            int row = rowbase + lk*4 + r;
            f32x4 res = po + hb4;
            *(f32x4*)(out + (size_t)row*4) = res;
        }
    }
}

extern "C" void kernel_launch(void* const* d_in, const int* in_sizes, int n_in,
                              void* d_out, int out_size, void* d_ws, size_t ws_size,
                              hipStream_t stream)
{
    const float* x    = (const float*)d_in[0];
    const float* ea   = (const float*)d_in[1];
    const int*   eidx = (const int*)d_in[2];
    const float* ew0  = (const float*)d_in[3];
    const float* eb0  = (const float*)d_in[4];
    const float* pw0  = (const float*)d_in[5];
    const float* pb0  = (const float*)d_in[6];
    const float* qw0  = (const float*)d_in[7];
    const float* qb0  = (const float*)d_in[8];
    const float* lw0  = (const float*)d_in[9];
    const float* lb0  = (const float*)d_in[10];
    const float* g0   = (const float*)d_in[11];
    const float* bl0  = (const float*)d_in[12];
    const float* ew1  = (const float*)d_in[13];
    const float* eb1  = (const float*)d_in[14];
    const float* pw1  = (const float*)d_in[15];
    const float* pb1  = (const float*)d_in[16];
    const float* qw1  = (const float*)d_in[17];
    const float* qb1  = (const float*)d_in[18];
    const float* lw1  = (const float*)d_in[19];
    const float* lb1  = (const float*)d_in[20];
    const float* g1   = (const float*)d_in[21];
    const float* bl1  = (const float*)d_in[22];
    const float* hw   = (const float*)d_in[23];
    const float* hb   = (const float*)d_in[24];
    const int* src = eidx;              // edge_index[0] = first E entries
    float* ws = (float*)d_ws;
    float* out = (float*)d_out;

    k_prep<<<2867, 256, 0, stream>>>(x, ew0, eb0, pw0, pb0, qw0, qb0, lw0, lb0,
                                     ew1, eb1, pw1, pb1, qw1, qb1, lw1, lb1, ws);
    k_pack<<<56, 256, 0, stream>>>(pw1, ws);
    k_agg0<<<1250, 256, 0, stream>>>(x, ea, src, ws);
    k_gemm0<<<625, 256, 0, stream>>>(g0, bl0, ws);
    k_tu1<<<1250, 64, 0, stream>>>(ws);
    k_agg1<<<1250, 256, 0, stream>>>(ea, src, ws);
    k_gemm1<<<1250, 64, 0, stream>>>(g1, bl1, hw, hb, ws, out);
}